// Round 5
// baseline (176.344 us; speedup 1.0000x reference)
//
#include <hip/hip_runtime.h>
#include <hip/hip_fp16.h>

#define NN 1536      // n_nodes
#define FDIM 32      // p == fts == 32
#define TG 96        // GEMM tile (grid 16x16 = 256 blocks = 1/CU)
#define KS 64        // i8 K-step (one mfma_16x16x64 worth of K)
#define NT (NN / KS) // 24 K-tiles

typedef __attribute__((ext_vector_type(4))) int i32x4;
typedef _Float16 h16x2 __attribute__((ext_vector_type(2)));

typedef __attribute__((address_space(3))) unsigned char as3_u8;
typedef __attribute__((address_space(1))) unsigned char as1_u8;

__device__ __forceinline__ void gload_lds16(const void* g, void* l) {
    __builtin_amdgcn_global_load_lds((const as1_u8*)g, (as3_u8*)l, 16, 0, 0);
}

// ---------------------------------------------------------------------------
// absmax(A) -> ws scalar (uint-compare == float-compare for non-negative f32)
// ---------------------------------------------------------------------------
__global__ __launch_bounds__(256) void gud_absmax(const float* __restrict__ A,
                                                  unsigned* __restrict__ amax) {
    int gid = blockIdx.x * 256 + threadIdx.x;
    float4 v = reinterpret_cast<const float4*>(A)[gid];
    float m = fmaxf(fmaxf(fabsf(v.x), fabsf(v.y)), fmaxf(fabsf(v.z), fabsf(v.w)));
#pragma unroll
    for (int k = 32; k >= 1; k >>= 1)
        m = fmaxf(m, __shfl_xor(m, k, 64));
    if ((threadIdx.x & 63) == 0)
        atomicMax(amax, __float_as_uint(m));
}

// ---------------------------------------------------------------------------
// Quantize A to 15-bit fixed point: q = rint(A/s), s = amax/32639,
// H = (q+128)>>8 (i8), L = q - 256H (i8).  A ~= s*(256H + L).
// ---------------------------------------------------------------------------
__global__ __launch_bounds__(256) void gud_quant(const float* __restrict__ A,
                                                 const unsigned* __restrict__ amaxu,
                                                 unsigned char* __restrict__ qH,
                                                 unsigned char* __restrict__ qL) {
    const float inv = 32639.0f / __uint_as_float(*amaxu);
    int gid = blockIdx.x * 256 + threadIdx.x;
    float4 v = reinterpret_cast<const float4*>(A)[gid];
    unsigned hw = 0, lw = 0;
    float elems[4] = {v.x, v.y, v.z, v.w};
#pragma unroll
    for (int e = 0; e < 4; ++e) {
        int q  = (int)rintf(fminf(fmaxf(elems[e] * inv, -32639.f), 32639.f));
        int hh = (q + 128) >> 8;           // arithmetic shift: floor((q+128)/256)
        int ll = q - (hh << 8);            // in [-128,127]
        hw |= ((unsigned)(hh & 0xff)) << (8 * e);
        lw |= ((unsigned)(ll & 0xff)) << (8 * e);
    }
    reinterpret_cast<unsigned*>(qH)[gid] = hw;
    reinterpret_cast<unsigned*>(qL)[gid] = lw;
}

// ---------------------------------------------------------------------------
// Prep: Q_l = P @ W1[l] for l = 1,2.  f16 outputs:
// QIh[i][l*32+f] = f16(Q + b1),  RJh[j][l*32+f] = f16(-Q).
// ---------------------------------------------------------------------------
__global__ __launch_bounds__(256) void gud_prep(const float* __restrict__ P,
                                                const float* __restrict__ W1,
                                                const float* __restrict__ b1,
                                                _Float16* __restrict__ QIh,
                                                _Float16* __restrict__ RJh) {
    int gid = blockIdx.x * 256 + threadIdx.x;   // 0 .. NN*64-1
    int i  = gid >> 6;
    int lf = gid & 63;
    int l  = (lf >> 5) + 1;   // 1 or 2
    int f  = lf & 31;
    const float* prow = P + i * FDIM;
    const float* w    = W1 + l * FDIM * FDIM + f;
    float q = 0.f;
#pragma unroll
    for (int c = 0; c < FDIM; ++c) q = fmaf(prow[c], w[c * FDIM], q);
    QIh[i * 64 + lf] = (_Float16)(q + b1[l * FDIM + f]);
    RJh[i * 64 + lf] = (_Float16)(-q);
}

// ---------------------------------------------------------------------------
// Fused i8 MFMA GEMM + conv epilogue.  A symmetric -> B-operand = rows j0.
//   A2 = s^2 * (65536*H.H + 256*(H.L + L.H))   (L.L dropped, ~2^-16 rel)
//   out[i,j] = A[i,j]*(m1+bb1) + A2[i,j]*(m2+bb2) + (i==j)*c0
// Round-3 pipeline: 3 LDS buffers, 2-deep prefetch, counted vmcnt(6),
// XOR-swizzled 64B row-chunks (inverse swizzle on global source).
// ---------------------------------------------------------------------------
__global__ __launch_bounds__(256, 1) void gud_gemm(
        const unsigned char* __restrict__ qH,
        const unsigned char* __restrict__ qL,
        const unsigned* __restrict__ amaxu,
        const float* __restrict__ A,
        const _Float16* __restrict__ QIh,
        const _Float16* __restrict__ RJh,
        const float* __restrict__ b1,
        const float* __restrict__ W2,
        const float* __restrict__ b2,
        float* __restrict__ out) {
    // 3 gemm bufs (4 subtiles x 96 rows x 64B = 24576B each) + QI/RJ (12288B ea)
    __shared__ char smem[3 * 24576 + 2 * 12288];   // 98304 B
    char* QIl = smem + 73728;
    char* RJl = QIl + 12288;

    const int tid  = threadIdx.x;
    const int lane = tid & 63;
    const int w    = tid >> 6;          // wave 0..3
    const int wr   = w >> 1, wc = w & 1;
    const int i0   = blockIdx.y * TG;
    const int j0   = blockIdx.x * TG;

    // ---- stage QI/RJ first (oldest in vmcnt FIFO). Transposed f16 layout:
    // 16B slot (c*96 + row) = QIh[i0+row][8c .. 8c+7].
#pragma unroll
    for (int sl = 0; sl < 3; ++sl) {
        int base = (w * 3 + sl) * 64;       // wave-uniform slot base
        int idx  = base + lane;
        int c    = idx / 96;
        int row  = idx - c * 96;
        gload_lds16(QIh + (size_t)(i0 + row) * 64 + c * 8, QIl + base * 16);
    }
#pragma unroll
    for (int sl = 0; sl < 3; ++sl) {
        int base = (w * 3 + sl) * 64;
        int idx  = base + lane;
        int c    = idx / 96;
        int row  = idx - c * 96;
        gload_lds16(RJh + (size_t)(j0 + row) * 64 + c * 8, RJl + base * 16);
    }

    // ---- GEMM staging: wave w owns subtile w (0=H@i0, 1=L@i0, 2=H@j0, 3=L@j0)
    const unsigned char* src = (w & 1) ? qL : qH;
    const int rowbase = (w < 2) ? i0 : j0;
    int goffs[6];
#pragma unroll
    for (int s = 0; s < 6; ++s) {
        int rt    = 16 * s + (lane >> 2);          // row within tile 0..95
        int chunk = (lane & 3) ^ ((rt >> 1) & 3);  // inverse swizzle on source
        goffs[s]  = (rowbase + rt) * NN + chunk * 16;   // i8: row stride NN bytes
    }

    // ---- fragment read offsets (swizzled); rows of 64B = K=64 i8
    int aoff[3], boff[3];
    const int kb = lane >> 4;
#pragma unroll
    for (int m = 0; m < 3; ++m) {
        int ra  = wr * 48 + m * 16 + (lane & 15);
        aoff[m] = ra * 64 + ((kb ^ ((ra >> 1) & 3)) * 16);
        int rb  = wc * 48 + m * 16 + (lane & 15);
        boff[m] = rb * 64 + ((kb ^ ((rb >> 1) & 3)) * 16);
    }

    i32x4 accH[3][3], accX[3][3];
#pragma unroll
    for (int m = 0; m < 3; ++m)
#pragma unroll
        for (int n = 0; n < 3; ++n) {
            accH[m][n] = (i32x4){0, 0, 0, 0};
            accX[m][n] = (i32x4){0, 0, 0, 0};
        }

    // ---- prologue: stage k-tiles 0,1 into buffers 0,1
#pragma unroll
    for (int s = 0; s < 6; ++s)
        gload_lds16((const char*)src + goffs[s], smem + w * 6144 + s * 1024);
#pragma unroll
    for (int s = 0; s < 6; ++s)
        gload_lds16((const char*)src + goffs[s] + KS, smem + 24576 + w * 6144 + s * 1024);

    auto compute = [&](const char* buf) {
        i32x4 hA[3], lA[3], hB[3], lB[3];
#pragma unroll
        for (int m = 0; m < 3; ++m) {
            hA[m] = *(const i32x4*)(buf + 0     + aoff[m]);
            lA[m] = *(const i32x4*)(buf + 6144  + aoff[m]);
            hB[m] = *(const i32x4*)(buf + 12288 + boff[m]);
            lB[m] = *(const i32x4*)(buf + 18432 + boff[m]);
        }
#pragma unroll
        for (int m = 0; m < 3; ++m)
#pragma unroll
            for (int n = 0; n < 3; ++n) {
                accH[m][n] = __builtin_amdgcn_mfma_i32_16x16x64_i8(hA[m], hB[n], accH[m][n], 0, 0, 0);
                accX[m][n] = __builtin_amdgcn_mfma_i32_16x16x64_i8(hA[m], lB[n], accX[m][n], 0, 0, 0);
                accX[m][n] = __builtin_amdgcn_mfma_i32_16x16x64_i8(lA[m], hB[n], accX[m][n], 0, 0, 0);
            }
    };

    // ---- main loop: vmcnt(6) retires tile kt (kt+1's 6 stay in flight)
    for (int kt = 0; kt < NT - 1; ++kt) {
        asm volatile("s_waitcnt vmcnt(6)" ::: "memory");
        __builtin_amdgcn_s_barrier();
        if (kt + 2 < NT) {   // stage kt+2 AFTER barrier (its buffer is now free)
            char* dst = smem + ((kt + 2) % 3) * 24576 + w * 6144;
            const int kbyte = (kt + 2) * KS;
#pragma unroll
            for (int s = 0; s < 6; ++s)
                gload_lds16((const char*)src + goffs[s] + kbyte, dst + s * 1024);
        }
        compute(smem + (kt % 3) * 24576);
    }
    asm volatile("s_waitcnt vmcnt(0)" ::: "memory");
    __builtin_amdgcn_s_barrier();
    compute(smem + ((NT - 1) % 3) * 24576);

    // ================= fused conv epilogue (f16 dot2) =================
    const int crow = (lane >> 4) * 4;
    const int ccol = lane & 15;
    int il[3], jl[3];
#pragma unroll
    for (int m = 0; m < 3; ++m) il[m] = wr * 48 + m * 16 + crow;
#pragma unroll
    for (int n = 0; n < 3; ++n) jl[n] = wc * 48 + n * 16 + ccol;

    // A values (issued early; land under the m1/m2 VALU work)
    float av[3][3][4];
#pragma unroll
    for (int m = 0; m < 3; ++m)
#pragma unroll
        for (int n = 0; n < 3; ++n)
#pragma unroll
            for (int r = 0; r < 4; ++r)
                av[m][n][r] = A[(size_t)(i0 + il[m] + r) * NN + j0 + jl[n]];

    const float s  = __uint_as_float(*amaxu) / 32639.0f;
    const float c1 = s * s * 65536.0f;
    const float c2 = s * s * 256.0f;

    float c0 = b2[0];
#pragma unroll
    for (int f = 0; f < FDIM; ++f) c0 = fmaf(fmaxf(b1[f], 0.f), W2[f], c0);
    const float bb1 = b2[1], bb2 = b2[2];

    // W2 layers 1,2 concat (feature f -> W2[32+f]) as f16 pairs
    h16x2 w2h[32];
#pragma unroll
    for (int k = 0; k < 32; ++k) {
        h16x2 t; t.x = (_Float16)W2[32 + 2 * k]; t.y = (_Float16)W2[33 + 2 * k];
        w2h[k] = t;
    }

    float m1[3][3][4], m2[3][3][4];
#pragma unroll
    for (int m = 0; m < 3; ++m)
#pragma unroll
        for (int n = 0; n < 3; ++n)
#pragma unroll
            for (int r = 0; r < 4; ++r) { m1[m][n][r] = 0.f; m2[m][n][r] = 0.f; }

#pragma unroll
    for (int c = 0; c < 8; ++c) {              // 8 chunks x 8 f16 features
        uint4 rv[3];
#pragma unroll
        for (int n = 0; n < 3; ++n)
            rv[n] = *(const uint4*)(RJl + (c * 96 + jl[n]) * 16);
        uint4 qv[3][4];
#pragma unroll
        for (int m = 0; m < 3; ++m)
#pragma unroll
            for (int r = 0; r < 4; ++r)
                qv[m][r] = *(const uint4*)(QIl + (c * 96 + il[m] + r) * 16);
#pragma unroll
        for (int m = 0; m < 3; ++m)
#pragma unroll
            for (int n = 0; n < 3; ++n) {
                const unsigned* ru = (const unsigned*)&rv[n];
#pragma unroll
                for (int r = 0; r < 4; ++r) {
                    const unsigned* qu = (const unsigned*)&qv[m][r];
                    float acc_f = (c < 4) ? m1[m][n][r] : m2[m][n][r];
#pragma unroll
                    for (int e = 0; e < 4; ++e) {
                        h16x2 q = __builtin_bit_cast(h16x2, qu[e]);
                        h16x2 j = __builtin_bit_cast(h16x2, ru[e]);
                        h16x2 h = q + j;                       // v_pk_add_f16
                        h16x2 z = {(_Float16)0, (_Float16)0};
                        h = __builtin_elementwise_max(h, z);   // v_pk_max_f16
                        acc_f = __builtin_amdgcn_fdot2(h, w2h[c * 4 + e], acc_f, false);
                    }
                    if (c < 4) m1[m][n][r] = acc_f; else m2[m][n][r] = acc_f;
                }
            }
    }

    // ---- final: out = A*(m1+bb1) + A2*(m2+bb2) + diag(c0)
#pragma unroll
    for (int m = 0; m < 3; ++m)
#pragma unroll
        for (int n = 0; n < 3; ++n)
#pragma unroll
            for (int r = 0; r < 4; ++r) {
                float a2 = c1 * (float)accH[m][n][r] + c2 * (float)accX[m][n][r];
                float v  = av[m][n][r] * (m1[m][n][r] + bb1)
                         + a2 * (m2[m][n][r] + bb2);
                int gi = i0 + il[m] + r;
                int gj = j0 + jl[n];
                if (gi == gj) v += c0;
                out[(size_t)gi * NN + gj] = v;
            }
}

// ---------------------------------------------------------------------------
extern "C" void kernel_launch(void* const* d_in, const int* in_sizes, int n_in,
                              void* d_out, int out_size, void* d_ws, size_t ws_size,
                              hipStream_t stream) {
    const float* A  = (const float*)d_in[0];   // [NN,NN] A_norm (symmetric)
    const float* P  = (const float*)d_in[1];   // [NN,32]
    const float* W1 = (const float*)d_in[2];   // [3,32,32]
    const float* b1 = (const float*)d_in[3];   // [3,32]
    const float* W2 = (const float*)d_in[4];   // [3,32,1]
    const float* b2 = (const float*)d_in[5];   // [3,1]
    float* out = (float*)d_out;

    unsigned char* qH = (unsigned char*)d_ws;                    // NN*NN i8
    unsigned char* qL = qH + (size_t)NN * NN;                    // NN*NN i8
    _Float16* QIh = (_Float16*)(qL + (size_t)NN * NN);           // NN*64 f16
    _Float16* RJh = QIh + (size_t)NN * 64;                       // NN*64 f16
    unsigned* amax = (unsigned*)(RJh + (size_t)NN * 64);         // 1 u32

    hipMemsetAsync(amax, 0, 4, stream);
    gud_absmax<<<dim3(NN * NN / 1024), 256, 0, stream>>>(A, amax);
    gud_quant<<<dim3(NN * NN / 1024), 256, 0, stream>>>(A, amax, qH, qL);
    gud_prep<<<dim3(NN * 64 / 256), 256, 0, stream>>>(P, W1, b1, QIh, RJh);
    gud_gemm<<<dim3(NN / TG, NN / TG), 256, 0, stream>>>(qH, qL, amax, A,
                                                         QIh, RJh, b1, W2, b2, out);
}

// Round 6
// 86.076 us; speedup vs baseline: 2.0487x; 2.0487x over previous
//
#include <hip/hip_runtime.h>
#include <hip/hip_fp16.h>

#define NN 1536      // n_nodes
#define FDIM 32      // p == fts == 32
#define TG 96        // GEMM tile (grid 16x16 = 256 blocks)
#define KS 64        // i8 K-step (one mfma_16x16x64 worth of K)
#define NT (NN / KS) // 24 K-tiles

typedef __attribute__((ext_vector_type(4))) int i32x4;
typedef _Float16 h16x2 __attribute__((ext_vector_type(2)));

typedef __attribute__((address_space(3))) unsigned char as3_u8;
typedef __attribute__((address_space(1))) unsigned char as1_u8;

__device__ __forceinline__ void gload_lds16(const void* g, void* l) {
    __builtin_amdgcn_global_load_lds((const as1_u8*)g, (as3_u8*)l, 16, 0, 0);
}

// ---------------------------------------------------------------------------
// absmax(A): 256 blocks grid-stride, wave shuffle-reduce, LDS cross-wave,
// ONE atomic per block (round-5's 9216 same-address atomics cost 107us).
// ---------------------------------------------------------------------------
__global__ __launch_bounds__(256) void gud_absmax(const float* __restrict__ A,
                                                  unsigned* __restrict__ amax) {
    __shared__ float red[4];
    const float4* A4 = reinterpret_cast<const float4*>(A);
    float m = 0.f;
    for (int idx = blockIdx.x * 256 + threadIdx.x; idx < NN * NN / 4;
         idx += 256 * 256) {
        float4 v = A4[idx];
        m = fmaxf(m, fmaxf(fmaxf(fabsf(v.x), fabsf(v.y)),
                           fmaxf(fabsf(v.z), fabsf(v.w))));
    }
#pragma unroll
    for (int k = 32; k >= 1; k >>= 1)
        m = fmaxf(m, __shfl_xor(m, k, 64));
    if ((threadIdx.x & 63) == 0) red[threadIdx.x >> 6] = m;
    __syncthreads();
    if (threadIdx.x == 0) {
        m = fmaxf(fmaxf(red[0], red[1]), fmaxf(red[2], red[3]));
        atomicMax(amax, __float_as_uint(m));
    }
}

// ---------------------------------------------------------------------------
// Quantize A to 15-bit fixed point: q = rint(A/s), s = amax/32639,
// H = (q+128)>>8 (i8), L = q - 256H (i8).  A ~= s*(256H + L).
// ---------------------------------------------------------------------------
__global__ __launch_bounds__(256) void gud_quant(const float* __restrict__ A,
                                                 const unsigned* __restrict__ amaxu,
                                                 unsigned char* __restrict__ qH,
                                                 unsigned char* __restrict__ qL) {
    const float inv = 32639.0f / __uint_as_float(*amaxu);
    int gid = blockIdx.x * 256 + threadIdx.x;
    float4 v = reinterpret_cast<const float4*>(A)[gid];
    unsigned hw = 0, lw = 0;
    float elems[4] = {v.x, v.y, v.z, v.w};
#pragma unroll
    for (int e = 0; e < 4; ++e) {
        int q  = (int)rintf(fminf(fmaxf(elems[e] * inv, -32639.f), 32639.f));
        int hh = (q + 128) >> 8;           // floor((q+128)/256)
        int ll = q - (hh << 8);            // in [-128,127]
        hw |= ((unsigned)(hh & 0xff)) << (8 * e);
        lw |= ((unsigned)(ll & 0xff)) << (8 * e);
    }
    reinterpret_cast<unsigned*>(qH)[gid] = hw;
    reinterpret_cast<unsigned*>(qL)[gid] = lw;
}

// ---------------------------------------------------------------------------
// Prep: Q_l = P @ W1[l] for l = 1,2.  f16 outputs:
// QIh[i][l*32+f] = f16(Q + b1),  RJh[j][l*32+f] = f16(-Q).
// ---------------------------------------------------------------------------
__global__ __launch_bounds__(256) void gud_prep(const float* __restrict__ P,
                                                const float* __restrict__ W1,
                                                const float* __restrict__ b1,
                                                _Float16* __restrict__ QIh,
                                                _Float16* __restrict__ RJh) {
    int gid = blockIdx.x * 256 + threadIdx.x;   // 0 .. NN*64-1
    int i  = gid >> 6;
    int lf = gid & 63;
    int l  = (lf >> 5) + 1;   // 1 or 2
    int f  = lf & 31;
    const float* prow = P + i * FDIM;
    const float* w    = W1 + l * FDIM * FDIM + f;
    float q = 0.f;
#pragma unroll
    for (int c = 0; c < FDIM; ++c) q = fmaf(prow[c], w[c * FDIM], q);
    QIh[i * 64 + lf] = (_Float16)(q + b1[l * FDIM + f]);
    RJh[i * 64 + lf] = (_Float16)(-q);
}

// ---------------------------------------------------------------------------
// Fused i8 MFMA GEMM + conv epilogue.  A symmetric -> B-operand = rows j0.
//   A2 = s^2 * (65536*H.H + 256*(H.L + L.H))   (L.L dropped, ~2^-16 rel)
//   out[i,j] = A[i,j]*(m1+bb1) + A2[i,j]*(m2+bb2) + (i==j)*c0
// 2-phase double-buffer (T3 minimal recipe): STAGE(buf^1) -> compute(buf) ->
// vmcnt(0)+barrier. LDS 72KB -> 2 blocks/CU fills the drain bubble.
// ---------------------------------------------------------------------------
__global__ __launch_bounds__(256, 2) void gud_gemm(
        const unsigned char* __restrict__ qH,
        const unsigned char* __restrict__ qL,
        const unsigned* __restrict__ amaxu,
        const float* __restrict__ A,
        const _Float16* __restrict__ QIh,
        const _Float16* __restrict__ RJh,
        const float* __restrict__ b1,
        const float* __restrict__ W2,
        const float* __restrict__ b2,
        float* __restrict__ out) {
    // 2 gemm bufs (4 subtiles x 96 rows x 64B = 24576B each) + QI/RJ (12288B ea)
    __shared__ char smem[2 * 24576 + 2 * 12288];   // 73728 B -> 2 blocks/CU
    char* QIl = smem + 49152;
    char* RJl = smem + 61440;

    const int tid  = threadIdx.x;
    const int lane = tid & 63;
    const int w    = tid >> 6;          // wave 0..3
    const int wr   = w >> 1, wc = w & 1;
    const int i0   = blockIdx.y * TG;
    const int j0   = blockIdx.x * TG;

    // ---- stage QI/RJ (transposed f16 layout: 16B slot (c*96+row) =
    // QIh[i0+row][8c..8c+7]); drained by the prologue vmcnt(0).
#pragma unroll
    for (int sl = 0; sl < 3; ++sl) {
        int base = (w * 3 + sl) * 64;       // wave-uniform slot base
        int idx  = base + lane;
        int c    = idx / 96;
        int row  = idx - c * 96;
        gload_lds16(QIh + (size_t)(i0 + row) * 64 + c * 8, QIl + base * 16);
    }
#pragma unroll
    for (int sl = 0; sl < 3; ++sl) {
        int base = (w * 3 + sl) * 64;
        int idx  = base + lane;
        int c    = idx / 96;
        int row  = idx - c * 96;
        gload_lds16(RJh + (size_t)(j0 + row) * 64 + c * 8, RJl + base * 16);
    }

    // ---- GEMM staging: wave w owns subtile w (0=H@i0, 1=L@i0, 2=H@j0, 3=L@j0)
    const unsigned char* src = (w & 1) ? qL : qH;
    const int rowbase = (w < 2) ? i0 : j0;
    int goffs[6];
#pragma unroll
    for (int s = 0; s < 6; ++s) {
        int rt    = 16 * s + (lane >> 2);          // row within tile 0..95
        int chunk = (lane & 3) ^ ((rt >> 1) & 3);  // inverse swizzle on source
        goffs[s]  = (rowbase + rt) * NN + chunk * 16;   // i8: row stride NN bytes
    }

    // ---- fragment read offsets (swizzled); rows of 64B = K=64 i8
    int aoff[3], boff[3];
    const int kb = lane >> 4;
#pragma unroll
    for (int m = 0; m < 3; ++m) {
        int ra  = wr * 48 + m * 16 + (lane & 15);
        aoff[m] = ra * 64 + ((kb ^ ((ra >> 1) & 3)) * 16);
        int rb  = wc * 48 + m * 16 + (lane & 15);
        boff[m] = rb * 64 + ((kb ^ ((rb >> 1) & 3)) * 16);
    }

    i32x4 accH[3][3], accX[3][3];
#pragma unroll
    for (int m = 0; m < 3; ++m)
#pragma unroll
        for (int n = 0; n < 3; ++n) {
            accH[m][n] = (i32x4){0, 0, 0, 0};
            accX[m][n] = (i32x4){0, 0, 0, 0};
        }

    auto compute = [&](const char* buf) {
        i32x4 hA[3], lA[3], hB[3], lB[3];
#pragma unroll
        for (int m = 0; m < 3; ++m) {
            hA[m] = *(const i32x4*)(buf + 0     + aoff[m]);
            lA[m] = *(const i32x4*)(buf + 6144  + aoff[m]);
            hB[m] = *(const i32x4*)(buf + 12288 + boff[m]);
            lB[m] = *(const i32x4*)(buf + 18432 + boff[m]);
        }
#pragma unroll
        for (int m = 0; m < 3; ++m)
#pragma unroll
            for (int n = 0; n < 3; ++n) {
                accH[m][n] = __builtin_amdgcn_mfma_i32_16x16x64_i8(hA[m], hB[n], accH[m][n], 0, 0, 0);
                accX[m][n] = __builtin_amdgcn_mfma_i32_16x16x64_i8(hA[m], lB[n], accX[m][n], 0, 0, 0);
                accX[m][n] = __builtin_amdgcn_mfma_i32_16x16x64_i8(lA[m], hB[n], accX[m][n], 0, 0, 0);
            }
    };

    // ---- prologue: stage k-tile 0 into buffer 0, drain, barrier
#pragma unroll
    for (int s = 0; s < 6; ++s)
        gload_lds16((const char*)src + goffs[s], smem + w * 6144 + s * 1024);
    asm volatile("s_waitcnt vmcnt(0)" ::: "memory");
    __builtin_amdgcn_s_barrier();

    // ---- main loop: STAGE(kt+1 -> buf^1) || compute(buf) ; vmcnt(0)+barrier
    int cur = 0;
    for (int kt = 0; kt < NT; ++kt) {
        if (kt + 1 < NT) {
            char* dst = smem + (cur ^ 1) * 24576 + w * 6144;
            const int kbyte = (kt + 1) * KS;
#pragma unroll
            for (int s = 0; s < 6; ++s)
                gload_lds16((const char*)src + goffs[s] + kbyte, dst + s * 1024);
        }
        compute(smem + cur * 24576);
        asm volatile("s_waitcnt vmcnt(0)" ::: "memory");
        __builtin_amdgcn_s_barrier();
        cur ^= 1;
    }

    // ================= fused conv epilogue (f16 dot2) =================
    const int crow = (lane >> 4) * 4;
    const int ccol = lane & 15;
    int il[3], jl[3];
#pragma unroll
    for (int m = 0; m < 3; ++m) il[m] = wr * 48 + m * 16 + crow;
#pragma unroll
    for (int n = 0; n < 3; ++n) jl[n] = wc * 48 + n * 16 + ccol;

    // A values (issued early; land under the m1/m2 VALU work)
    float av[3][3][4];
#pragma unroll
    for (int m = 0; m < 3; ++m)
#pragma unroll
        for (int n = 0; n < 3; ++n)
#pragma unroll
            for (int r = 0; r < 4; ++r)
                av[m][n][r] = A[(size_t)(i0 + il[m] + r) * NN + j0 + jl[n]];

    const float s  = __uint_as_float(*amaxu) / 32639.0f;
    const float c1 = s * s * 65536.0f;
    const float c2 = s * s * 256.0f;

    float c0 = b2[0];
#pragma unroll
    for (int f = 0; f < FDIM; ++f) c0 = fmaf(fmaxf(b1[f], 0.f), W2[f], c0);
    const float bb1 = b2[1], bb2 = b2[2];

    // W2 layers 1,2 concat (feature f -> W2[32+f]) as f16 pairs
    h16x2 w2h[32];
#pragma unroll
    for (int k = 0; k < 32; ++k) {
        h16x2 t; t.x = (_Float16)W2[32 + 2 * k]; t.y = (_Float16)W2[33 + 2 * k];
        w2h[k] = t;
    }

    float m1[3][3][4], m2[3][3][4];
#pragma unroll
    for (int m = 0; m < 3; ++m)
#pragma unroll
        for (int n = 0; n < 3; ++n)
#pragma unroll
            for (int r = 0; r < 4; ++r) { m1[m][n][r] = 0.f; m2[m][n][r] = 0.f; }

#pragma unroll
    for (int c = 0; c < 8; ++c) {              // 8 chunks x 8 f16 features
        uint4 rv[3];
#pragma unroll
        for (int n = 0; n < 3; ++n)
            rv[n] = *(const uint4*)(RJl + (c * 96 + jl[n]) * 16);
        uint4 qv[3][4];
#pragma unroll
        for (int m = 0; m < 3; ++m)
#pragma unroll
            for (int r = 0; r < 4; ++r)
                qv[m][r] = *(const uint4*)(QIl + (c * 96 + il[m] + r) * 16);
#pragma unroll
        for (int m = 0; m < 3; ++m)
#pragma unroll
            for (int n = 0; n < 3; ++n) {
                const unsigned* ru = (const unsigned*)&rv[n];
#pragma unroll
                for (int r = 0; r < 4; ++r) {
                    const unsigned* qu = (const unsigned*)&qv[m][r];
                    float acc_f = (c < 4) ? m1[m][n][r] : m2[m][n][r];
#pragma unroll
                    for (int e = 0; e < 4; ++e) {
                        h16x2 q = __builtin_bit_cast(h16x2, qu[e]);
                        h16x2 j = __builtin_bit_cast(h16x2, ru[e]);
                        h16x2 h = q + j;                       // v_pk_add_f16
                        h16x2 z = {(_Float16)0, (_Float16)0};
                        h = __builtin_elementwise_max(h, z);   // v_pk_max_f16
                        acc_f = __builtin_amdgcn_fdot2(h, w2h[c * 4 + e], acc_f, false);
                    }
                    if (c < 4) m1[m][n][r] = acc_f; else m2[m][n][r] = acc_f;
                }
            }
    }

    // ---- final: out = A*(m1+bb1) + A2*(m2+bb2) + diag(c0)
#pragma unroll
    for (int m = 0; m < 3; ++m)
#pragma unroll
        for (int n = 0; n < 3; ++n)
#pragma unroll
            for (int r = 0; r < 4; ++r) {
                float a2 = c1 * (float)accH[m][n][r] + c2 * (float)accX[m][n][r];
                float v  = av[m][n][r] * (m1[m][n][r] + bb1)
                         + a2 * (m2[m][n][r] + bb2);
                int gi = i0 + il[m] + r;
                int gj = j0 + jl[n];
                if (gi == gj) v += c0;
                out[(size_t)gi * NN + gj] = v;
            }
}

// ---------------------------------------------------------------------------
extern "C" void kernel_launch(void* const* d_in, const int* in_sizes, int n_in,
                              void* d_out, int out_size, void* d_ws, size_t ws_size,
                              hipStream_t stream) {
    const float* A  = (const float*)d_in[0];   // [NN,NN] A_norm (symmetric)
    const float* P  = (const float*)d_in[1];   // [NN,32]
    const float* W1 = (const float*)d_in[2];   // [3,32,32]
    const float* b1 = (const float*)d_in[3];   // [3,32]
    const float* W2 = (const float*)d_in[4];   // [3,32,1]
    const float* b2 = (const float*)d_in[5];   // [3,1]
    float* out = (float*)d_out;

    unsigned char* qH = (unsigned char*)d_ws;                    // NN*NN i8
    unsigned char* qL = qH + (size_t)NN * NN;                    // NN*NN i8
    _Float16* QIh = (_Float16*)(qL + (size_t)NN * NN);           // NN*64 f16
    _Float16* RJh = QIh + (size_t)NN * 64;                       // NN*64 f16
    unsigned* amax = (unsigned*)(RJh + (size_t)NN * 64);         // 1 u32

    hipMemsetAsync(amax, 0, 4, stream);
    gud_absmax<<<dim3(256), 256, 0, stream>>>(A, amax);
    gud_quant<<<dim3(NN * NN / 1024), 256, 0, stream>>>(A, amax, qH, qL);
    gud_prep<<<dim3(NN * 64 / 256), 256, 0, stream>>>(P, W1, b1, QIh, RJh);
    gud_gemm<<<dim3(NN / TG, NN / TG), 256, 0, stream>>>(qH, qL, amax, A,
                                                         QIh, RJh, b1, W2, b2, out);
}

// Round 7
// 61.276 us; speedup vs baseline: 2.8779x; 1.4047x over previous
//
#include <hip/hip_runtime.h>
#include <hip/hip_fp16.h>

#define NN 1536      // n_nodes
#define FDIM 32      // p == fts == 32
#define TG 96        // GEMM tile (grid 16x16 = 256 blocks)
#define KS 32        // K-step (one mfma_16x16x32 worth of K)
#define NT (NN / KS) // 48 K-tiles

typedef __attribute__((ext_vector_type(8))) __bf16 bf16x8;
typedef __attribute__((ext_vector_type(4))) float f32x4;
typedef _Float16 h16x2 __attribute__((ext_vector_type(2)));

typedef __attribute__((address_space(3))) unsigned char as3_u8;
typedef __attribute__((address_space(1))) unsigned char as1_u8;

__device__ __forceinline__ void gload_lds16(const void* g, void* l) {
    __builtin_amdgcn_global_load_lds((const as1_u8*)g, (as3_u8*)l, 16, 0, 0);
}

// ---------------------------------------------------------------------------
// Split A into bf16 hi/lo: Ah = rne_bf16(a), Al = rne_bf16(a - float(Ah)).
// ---------------------------------------------------------------------------
__device__ __forceinline__ unsigned short bf16rne(float f) {
    unsigned u = __float_as_uint(f);
    return (unsigned short)((u + 0x7FFFu + ((u >> 16) & 1u)) >> 16);
}

__global__ __launch_bounds__(256) void gud_split(const float* __restrict__ A,
                                                 unsigned short* __restrict__ Ah,
                                                 unsigned short* __restrict__ Al) {
    int gid = blockIdx.x * 256 + threadIdx.x;      // 4 floats per thread
    float4 v = reinterpret_cast<const float4*>(A)[gid];
    ushort4 h, l;
    float x;
    x = v.x; h.x = bf16rne(x); l.x = bf16rne(x - __uint_as_float((unsigned)h.x << 16));
    x = v.y; h.y = bf16rne(x); l.y = bf16rne(x - __uint_as_float((unsigned)h.y << 16));
    x = v.z; h.z = bf16rne(x); l.z = bf16rne(x - __uint_as_float((unsigned)h.z << 16));
    x = v.w; h.w = bf16rne(x); l.w = bf16rne(x - __uint_as_float((unsigned)h.w << 16));
    reinterpret_cast<ushort4*>(Ah)[gid] = h;
    reinterpret_cast<ushort4*>(Al)[gid] = l;
}

// ---------------------------------------------------------------------------
// Prep: Q_l = P @ W1[l] for l = 1,2.  f16 outputs:
// QIh[i][l*32+f] = f16(Q + b1),  RJh[j][l*32+f] = f16(-Q).
// ---------------------------------------------------------------------------
__global__ __launch_bounds__(256) void gud_prep(const float* __restrict__ P,
                                                const float* __restrict__ W1,
                                                const float* __restrict__ b1,
                                                _Float16* __restrict__ QIh,
                                                _Float16* __restrict__ RJh) {
    int gid = blockIdx.x * 256 + threadIdx.x;   // 0 .. NN*64-1
    int i  = gid >> 6;
    int lf = gid & 63;
    int l  = (lf >> 5) + 1;   // 1 or 2
    int f  = lf & 31;
    const float* prow = P + i * FDIM;
    const float* w    = W1 + l * FDIM * FDIM + f;
    float q = 0.f;
#pragma unroll
    for (int c = 0; c < FDIM; ++c) q = fmaf(prow[c], w[c * FDIM], q);
    QIh[i * 64 + lf] = (_Float16)(q + b1[l * FDIM + f]);
    RJh[i * 64 + lf] = (_Float16)(-q);
}

// ---------------------------------------------------------------------------
// Fused MFMA GEMM + conv epilogue.  A symmetric -> B-operand = rows j0.
//   acc = A*A via bf16 hi/lo (AhBh + AlBh + AhBl, ONE f32 accumulator)
//   out[i,j] = A[i,j]*(m1+bb1) + acc[i,j]*(m2+bb2) + (i==j)*c0
// 2-phase double-buffer: STAGE(kt+1 -> buf^1) || compute(buf); vmcnt(0)+bar.
// LDS 73728 B -> 2 blocks/CU; co-resident block fills the drain bubble.
// ---------------------------------------------------------------------------
__global__ __launch_bounds__(256, 2) void gud_gemm(
        const unsigned short* __restrict__ Ah,
        const unsigned short* __restrict__ Al,
        const float* __restrict__ A,
        const _Float16* __restrict__ QIh,
        const _Float16* __restrict__ RJh,
        const float* __restrict__ b1,
        const float* __restrict__ W2,
        const float* __restrict__ b2,
        float* __restrict__ out) {
    // 2 gemm bufs (4 subtiles x 96 rows x 64B = 24576B each) + QI/RJ f16 (12288B ea)
    __shared__ char smem[2 * 24576 + 2 * 12288];   // 73728 B
    char* QIl = smem + 49152;
    char* RJl = smem + 61440;

    const int tid  = threadIdx.x;
    const int lane = tid & 63;
    const int w    = tid >> 6;          // wave 0..3
    const int wr   = w >> 1, wc = w & 1;
    const int i0   = blockIdx.y * TG;
    const int j0   = blockIdx.x * TG;

    // ---- stage QI/RJ (transposed f16 layout: 16B slot (c*96+row) =
    // QIh[i0+row][8c..8c+7]); drained by the prologue vmcnt(0).
#pragma unroll
    for (int sl = 0; sl < 3; ++sl) {
        int base = (w * 3 + sl) * 64;       // wave-uniform slot base
        int idx  = base + lane;
        int c    = idx / 96;
        int row  = idx - c * 96;
        gload_lds16(QIh + (size_t)(i0 + row) * 64 + c * 8, QIl + base * 16);
    }
#pragma unroll
    for (int sl = 0; sl < 3; ++sl) {
        int base = (w * 3 + sl) * 64;
        int idx  = base + lane;
        int c    = idx / 96;
        int row  = idx - c * 96;
        gload_lds16(RJh + (size_t)(j0 + row) * 64 + c * 8, RJl + base * 16);
    }

    // ---- GEMM staging: wave w owns subtile w (0=Ah@i0, 1=Al@i0, 2=Ah@j0, 3=Al@j0)
    const unsigned short* src = (w & 1) ? Al : Ah;
    const int rowbase = (w < 2) ? i0 : j0;
    int goffs[6];
#pragma unroll
    for (int s = 0; s < 6; ++s) {
        int rt    = 16 * s + (lane >> 2);          // row within tile 0..95
        int chunk = (lane & 3) ^ ((rt >> 1) & 3);  // inverse swizzle on source
        goffs[s]  = (rowbase + rt) * (NN * 2) + chunk * 16;
    }

    // ---- fragment read offsets (swizzled); rows of 64B = K=32 bf16
    int aoff[3], boff[3];
    const int kb = lane >> 4;
#pragma unroll
    for (int m = 0; m < 3; ++m) {
        int ra  = wr * 48 + m * 16 + (lane & 15);
        aoff[m] = ra * 64 + ((kb ^ ((ra >> 1) & 3)) * 16);
        int rb  = wc * 48 + m * 16 + (lane & 15);
        boff[m] = rb * 64 + ((kb ^ ((rb >> 1) & 3)) * 16);
    }

    f32x4 acc[3][3];
#pragma unroll
    for (int m = 0; m < 3; ++m)
#pragma unroll
        for (int n = 0; n < 3; ++n) acc[m][n] = (f32x4){0.f, 0.f, 0.f, 0.f};

    auto compute = [&](const char* buf) {
        bf16x8 ahf[3], alf[3], bhf[3], blf[3];
#pragma unroll
        for (int m = 0; m < 3; ++m) {
            ahf[m] = *(const bf16x8*)(buf + 0     + aoff[m]);
            alf[m] = *(const bf16x8*)(buf + 6144  + aoff[m]);
            bhf[m] = *(const bf16x8*)(buf + 12288 + boff[m]);
            blf[m] = *(const bf16x8*)(buf + 18432 + boff[m]);
        }
#pragma unroll
        for (int m = 0; m < 3; ++m)
#pragma unroll
            for (int n = 0; n < 3; ++n) {
                acc[m][n] = __builtin_amdgcn_mfma_f32_16x16x32_bf16(ahf[m], bhf[n], acc[m][n], 0, 0, 0);
                acc[m][n] = __builtin_amdgcn_mfma_f32_16x16x32_bf16(alf[m], bhf[n], acc[m][n], 0, 0, 0);
                acc[m][n] = __builtin_amdgcn_mfma_f32_16x16x32_bf16(ahf[m], blf[n], acc[m][n], 0, 0, 0);
            }
    };

    // ---- prologue: stage k-tile 0 into buffer 0, drain, barrier
#pragma unroll
    for (int s = 0; s < 6; ++s)
        gload_lds16((const char*)src + goffs[s], smem + w * 6144 + s * 1024);
    asm volatile("s_waitcnt vmcnt(0)" ::: "memory");
    __builtin_amdgcn_s_barrier();

    // ---- main loop: STAGE(kt+1 -> buf^1) || compute(buf) ; vmcnt(0)+barrier
    int cur = 0;
    for (int kt = 0; kt < NT; ++kt) {
        if (kt + 1 < NT) {
            char* dst = smem + (cur ^ 1) * 24576 + w * 6144;
            const int kbyte = (kt + 1) * (KS * 2);
#pragma unroll
            for (int s = 0; s < 6; ++s)
                gload_lds16((const char*)src + goffs[s] + kbyte, dst + s * 1024);
        }
        compute(smem + cur * 24576);
        asm volatile("s_waitcnt vmcnt(0)" ::: "memory");
        __builtin_amdgcn_s_barrier();
        cur ^= 1;
    }

    // ================= fused conv epilogue (f16 dot2, two-pass) =================
    const int crow = (lane >> 4) * 4;
    const int ccol = lane & 15;
    int il[3], jl[3];
#pragma unroll
    for (int m = 0; m < 3; ++m) il[m] = wr * 48 + m * 16 + crow;
#pragma unroll
    for (int n = 0; n < 3; ++n) jl[n] = wc * 48 + n * 16 + ccol;

    // A values (issued early; land under the pass-1 VALU work)
    float av[3][3][4];
#pragma unroll
    for (int m = 0; m < 3; ++m)
#pragma unroll
        for (int n = 0; n < 3; ++n)
#pragma unroll
            for (int r = 0; r < 4; ++r)
                av[m][n][r] = A[(size_t)(i0 + il[m] + r) * NN + j0 + jl[n]];

    float c0 = b2[0];
#pragma unroll
    for (int f = 0; f < FDIM; ++f) c0 = fmaf(fmaxf(b1[f], 0.f), W2[f], c0);
    const float bb1 = b2[1], bb2 = b2[2];

    // W2 layers 1,2 concat (feature f -> W2[32+f]) as f16 pairs
    h16x2 w2h[32];
#pragma unroll
    for (int k = 0; k < 32; ++k) {
        h16x2 t; t.x = (_Float16)W2[32 + 2 * k]; t.y = (_Float16)W2[33 + 2 * k];
        w2h[k] = t;
    }

    float mm[3][3][4];

    // ---- pass 1: chunks 0..3 (features 0..31, layer 1) -> m1, fold into av
#pragma unroll
    for (int m = 0; m < 3; ++m)
#pragma unroll
        for (int n = 0; n < 3; ++n)
#pragma unroll
            for (int r = 0; r < 4; ++r) mm[m][n][r] = 0.f;
#pragma unroll
    for (int c = 0; c < 4; ++c) {
        uint4 rv[3];
#pragma unroll
        for (int n = 0; n < 3; ++n)
            rv[n] = *(const uint4*)(RJl + (c * 96 + jl[n]) * 16);
        uint4 qv[3][4];
#pragma unroll
        for (int m = 0; m < 3; ++m)
#pragma unroll
            for (int r = 0; r < 4; ++r)
                qv[m][r] = *(const uint4*)(QIl + (c * 96 + il[m] + r) * 16);
#pragma unroll
        for (int m = 0; m < 3; ++m)
#pragma unroll
            for (int n = 0; n < 3; ++n) {
                const unsigned* ru = (const unsigned*)&rv[n];
#pragma unroll
                for (int r = 0; r < 4; ++r) {
                    const unsigned* qu = (const unsigned*)&qv[m][r];
                    float acc_f = mm[m][n][r];
#pragma unroll
                    for (int e = 0; e < 4; ++e) {
                        h16x2 q = __builtin_bit_cast(h16x2, qu[e]);
                        h16x2 j = __builtin_bit_cast(h16x2, ru[e]);
                        h16x2 h = q + j;                       // v_pk_add_f16
                        h16x2 z = {(_Float16)0, (_Float16)0};
                        h = __builtin_elementwise_max(h, z);   // v_pk_max_f16
                        acc_f = __builtin_amdgcn_fdot2(h, w2h[c * 4 + e], acc_f, false);
                    }
                    mm[m][n][r] = acc_f;
                }
            }
    }
#pragma unroll
    for (int m = 0; m < 3; ++m)
#pragma unroll
        for (int n = 0; n < 3; ++n)
#pragma unroll
            for (int r = 0; r < 4; ++r)
                av[m][n][r] *= (mm[m][n][r] + bb1);

    // ---- pass 2: chunks 4..7 (features 32..63, layer 2) -> m2
#pragma unroll
    for (int m = 0; m < 3; ++m)
#pragma unroll
        for (int n = 0; n < 3; ++n)
#pragma unroll
            for (int r = 0; r < 4; ++r) mm[m][n][r] = 0.f;
#pragma unroll
    for (int c = 4; c < 8; ++c) {
        uint4 rv[3];
#pragma unroll
        for (int n = 0; n < 3; ++n)
            rv[n] = *(const uint4*)(RJl + (c * 96 + jl[n]) * 16);
        uint4 qv[3][4];
#pragma unroll
        for (int m = 0; m < 3; ++m)
#pragma unroll
            for (int r = 0; r < 4; ++r)
                qv[m][r] = *(const uint4*)(QIl + (c * 96 + il[m] + r) * 16);
#pragma unroll
        for (int m = 0; m < 3; ++m)
#pragma unroll
            for (int n = 0; n < 3; ++n) {
                const unsigned* ru = (const unsigned*)&rv[n];
#pragma unroll
                for (int r = 0; r < 4; ++r) {
                    const unsigned* qu = (const unsigned*)&qv[m][r];
                    float acc_f = mm[m][n][r];
#pragma unroll
                    for (int e = 0; e < 4; ++e) {
                        h16x2 q = __builtin_bit_cast(h16x2, qu[e]);
                        h16x2 j = __builtin_bit_cast(h16x2, ru[e]);
                        h16x2 h = q + j;
                        h16x2 z = {(_Float16)0, (_Float16)0};
                        h = __builtin_elementwise_max(h, z);
                        acc_f = __builtin_amdgcn_fdot2(h, w2h[c * 4 + e], acc_f, false);
                    }
                    mm[m][n][r] = acc_f;
                }
            }
    }

    // ---- final: out = A*(m1+bb1) + acc*(m2+bb2) + diag(c0)
#pragma unroll
    for (int m = 0; m < 3; ++m)
#pragma unroll
        for (int n = 0; n < 3; ++n)
#pragma unroll
            for (int r = 0; r < 4; ++r) {
                float v = av[m][n][r] + acc[m][n][r] * (mm[m][n][r] + bb2);
                int gi = i0 + il[m] + r;
                int gj = j0 + jl[n];
                if (gi == gj) v += c0;
                out[(size_t)gi * NN + gj] = v;
            }
}

// ---------------------------------------------------------------------------
extern "C" void kernel_launch(void* const* d_in, const int* in_sizes, int n_in,
                              void* d_out, int out_size, void* d_ws, size_t ws_size,
                              hipStream_t stream) {
    const float* A  = (const float*)d_in[0];   // [NN,NN] A_norm (symmetric)
    const float* P  = (const float*)d_in[1];   // [NN,32]
    const float* W1 = (const float*)d_in[2];   // [3,32,32]
    const float* b1 = (const float*)d_in[3];   // [3,32]
    const float* W2 = (const float*)d_in[4];   // [3,32,1]
    const float* b2 = (const float*)d_in[5];   // [3,1]
    float* out = (float*)d_out;

    unsigned short* Ahh = (unsigned short*)d_ws;                 // NN*NN bf16
    unsigned short* All = Ahh + (size_t)NN * NN;                 // NN*NN bf16
    _Float16* QIh = (_Float16*)(All + (size_t)NN * NN);          // NN*64 f16
    _Float16* RJh = QIh + (size_t)NN * 64;                       // NN*64 f16

    gud_split<<<dim3(NN * NN / 1024), 256, 0, stream>>>(A, Ahh, All);
    gud_prep<<<dim3(NN * 64 / 256), 256, 0, stream>>>(P, W1, b1, QIh, RJh);
    gud_gemm<<<dim3(NN / TG, NN / TG), 256, 0, stream>>>(Ahh, All, A, QIh, RJh,
                                                         b1, W2, b2, out);
}